// Round 1
// baseline (45.252 us; speedup 1.0000x reference)
//
#include <hip/hip_runtime.h>
#include <hip/hip_bf16.h>
#include <math.h>

// CBOW negative-sampling loss, collapsed:
//   out = -( (1/B) * sum_b logsig(dot(emb_w[target[b]], c_b))
//          + (1/B) * sum_b sum_k logsig(dot(emb_w[noise[b,k]], c_b)) )
//   c_b = mean_w ctx_w[context[b,w]]
// V=100000, D=128, B=16384, W=10, K=10.

#define CBOW_B 16384
#define CBOW_W 10
#define CBOW_K 10
#define CBOW_D 128
#define WAVES_PER_BLOCK 4
#define NBLOCKS (CBOW_B / WAVES_PER_BLOCK)   // 4096

__device__ __forceinline__ float log_sigmoid(float x) {
    // stable: min(x,0) - log1p(exp(-|x|))
    return fminf(x, 0.0f) - log1pf(__expf(-fabsf(x)));
}

__device__ __forceinline__ float wave_reduce_sum(float s) {
    #pragma unroll
    for (int m = 32; m >= 1; m >>= 1) s += __shfl_xor(s, m, 64);
    return s;
}

__global__ __launch_bounds__(256) void cbow_main(
    const int* __restrict__ context,   // [B, W]
    const int* __restrict__ target,    // [B]
    const int* __restrict__ noise,     // [B, K]
    const float* __restrict__ emb_w,   // [V, D]
    const float* __restrict__ ctx_w,   // [V, D]
    float* __restrict__ block_sums)    // [NBLOCKS]
{
    const int wave = threadIdx.x >> 6;
    const int lane = threadIdx.x & 63;
    const int b = blockIdx.x * WAVES_PER_BLOCK + wave;   // grid sized exactly

    const int elem = lane * 2;  // this lane owns floats [elem, elem+1] of D=128

    // ---- context mean-pool into registers (float2 per lane) ----
    float cx = 0.0f, cy = 0.0f;
    #pragma unroll
    for (int w = 0; w < CBOW_W; ++w) {
        const int idx = context[b * CBOW_W + w];
        const float2 r = *reinterpret_cast<const float2*>(
            &ctx_w[(long long)idx * CBOW_D + elem]);
        cx += r.x; cy += r.y;
    }
    cx *= (1.0f / CBOW_W);
    cy *= (1.0f / CBOW_W);

    // ---- positive score ----
    float sum = 0.0f;
    {
        const int idx = target[b];
        const float2 r = *reinterpret_cast<const float2*>(
            &emb_w[(long long)idx * CBOW_D + elem]);
        const float dot = wave_reduce_sum(cx * r.x + cy * r.y);
        sum += log_sigmoid(dot);
    }

    // ---- negative scores ----
    #pragma unroll
    for (int k = 0; k < CBOW_K; ++k) {
        const int idx = noise[b * CBOW_K + k];
        const float2 r = *reinterpret_cast<const float2*>(
            &emb_w[(long long)idx * CBOW_D + elem]);
        const float dot = wave_reduce_sum(cx * r.x + cy * r.y);
        sum += log_sigmoid(dot);
    }

    // ---- per-block partial sum (deterministic; no atomics) ----
    __shared__ float wsum[WAVES_PER_BLOCK];
    if (lane == 0) wsum[wave] = sum;
    __syncthreads();
    if (threadIdx.x == 0) {
        float s = 0.0f;
        #pragma unroll
        for (int i = 0; i < WAVES_PER_BLOCK; ++i) s += wsum[i];
        block_sums[blockIdx.x] = s;
    }
}

__global__ __launch_bounds__(256) void cbow_finish(
    const float* __restrict__ block_sums, float* __restrict__ out)
{
    __shared__ double sh[256];
    double s = 0.0;
    for (int i = threadIdx.x; i < NBLOCKS; i += 256) s += (double)block_sums[i];
    sh[threadIdx.x] = s;
    __syncthreads();
    #pragma unroll
    for (int stride = 128; stride >= 1; stride >>= 1) {
        if (threadIdx.x < stride) sh[threadIdx.x] += sh[threadIdx.x + stride];
        __syncthreads();
    }
    if (threadIdx.x == 0) {
        out[0] = (float)(-sh[0] / (double)CBOW_B);
    }
}

extern "C" void kernel_launch(void* const* d_in, const int* in_sizes, int n_in,
                              void* d_out, int out_size, void* d_ws, size_t ws_size,
                              hipStream_t stream) {
    const int*   context = (const int*)d_in[0];   // [B, W]
    const int*   target  = (const int*)d_in[1];   // [B]
    const int*   noise   = (const int*)d_in[2];   // [B, K]
    const float* emb_w   = (const float*)d_in[3]; // [V, D]
    const float* ctx_w   = (const float*)d_in[4]; // [V, D]
    float*       out     = (float*)d_out;
    float*       block_sums = (float*)d_ws;       // NBLOCKS floats = 16 KiB

    cbow_main<<<NBLOCKS, 256, 0, stream>>>(context, target, noise, emb_w, ctx_w,
                                           block_sums);
    cbow_finish<<<1, 256, 0, stream>>>(block_sums, out);
}

// Round 2
// 32.111 us; speedup vs baseline: 1.4092x; 1.4092x over previous
//
#include <hip/hip_runtime.h>
#include <hip/hip_bf16.h>
#include <math.h>

// CBOW negative-sampling loss, collapsed:
//   out = -( (1/B) * sum_b [ logsig(dot(emb_w[target[b]], c_b))
//                          + sum_k logsig(dot(emb_w[noise[b,k]], c_b)) ] )
//   c_b = mean_w ctx_w[context[b,w]]
// V=100000, D=128, B=16384, W=10, K=10.
//
// Partitioning: 16 lanes per batch row (each lane owns 8 floats of D=128),
// 4 rows per wave, 4 waves per block -> 16 rows/block, 1024 blocks.
// One shuffle instruction advances 4 rows' reductions at once.

#define CBOW_B 16384
#define CBOW_W 10
#define CBOW_K 10
#define CBOW_D 128
#define ROWS_PER_BLOCK 16
#define NBLOCKS (CBOW_B / ROWS_PER_BLOCK)   // 1024

__device__ __forceinline__ float log_sigmoid(float x) {
    // stable: min(x,0) - log(1 + exp(-|x|)); fast exp/log are plenty accurate here
    const float t = __expf(-fabsf(x));
    return fminf(x, 0.0f) - __logf(1.0f + t);
}

// sum across a 16-lane group (lanes sharing lane>>4)
__device__ __forceinline__ float group_reduce_sum(float s) {
    s += __shfl_xor(s, 8, 64);
    s += __shfl_xor(s, 4, 64);
    s += __shfl_xor(s, 2, 64);
    s += __shfl_xor(s, 1, 64);
    return s;
}

__global__ __launch_bounds__(256) void cbow_main(
    const int* __restrict__ context,   // [B, W]
    const int* __restrict__ target,    // [B]
    const int* __restrict__ noise,     // [B, K]
    const float* __restrict__ emb_w,   // [V, D]
    const float* __restrict__ ctx_w,   // [V, D]
    float* __restrict__ block_sums)    // [NBLOCKS]
{
    const int wave = threadIdx.x >> 6;
    const int lane = threadIdx.x & 63;
    const int grp  = lane >> 4;        // 0..3: which batch row within the wave
    const int sub  = lane & 15;        // lane within the 16-lane group
    const int b = blockIdx.x * ROWS_PER_BLOCK + wave * 4 + grp;

    const int elem = sub * 8;          // this lane owns floats [elem, elem+8)

    // ---- context mean-pool into registers (8 floats per lane) ----
    float c0x=0,c0y=0,c0z=0,c0w=0, c1x=0,c1y=0,c1z=0,c1w=0;
    #pragma unroll
    for (int w = 0; w < CBOW_W; ++w) {
        const int idx = context[b * CBOW_W + w];
        const float4* p = reinterpret_cast<const float4*>(
            &ctx_w[(long long)idx * CBOW_D + elem]);
        const float4 r0 = p[0];
        const float4 r1 = p[1];
        c0x += r0.x; c0y += r0.y; c0z += r0.z; c0w += r0.w;
        c1x += r1.x; c1y += r1.y; c1z += r1.z; c1w += r1.w;
    }
    const float inv = 1.0f / CBOW_W;
    c0x*=inv; c0y*=inv; c0z*=inv; c0w*=inv;
    c1x*=inv; c1y*=inv; c1z*=inv; c1w*=inv;

    // ---- positive + negative scores ----
    float sum = 0.0f;
    #pragma unroll
    for (int k = 0; k < CBOW_K + 1; ++k) {
        const int idx = (k == 0) ? target[b] : noise[b * CBOW_K + (k - 1)];
        const float4* p = reinterpret_cast<const float4*>(
            &emb_w[(long long)idx * CBOW_D + elem]);
        const float4 r0 = p[0];
        const float4 r1 = p[1];
        float part = c0x*r0.x + c0y*r0.y + c0z*r0.z + c0w*r0.w
                   + c1x*r1.x + c1y*r1.y + c1z*r1.z + c1w*r1.w;
        const float dot = group_reduce_sum(part);
        sum += log_sigmoid(dot);   // uniform within group; lockstep across groups
    }

    // ---- sum the 4 groups of this wave (uniform-within-group values) ----
    sum += __shfl_xor(sum, 16, 64);
    sum += __shfl_xor(sum, 32, 64);   // now every lane holds the wave total

    // ---- per-block partial sum (deterministic; no atomics) ----
    __shared__ float wsum[4];
    if (lane == 0) wsum[wave] = sum;
    __syncthreads();
    if (threadIdx.x == 0) {
        float s = 0.0f;
        #pragma unroll
        for (int i = 0; i < 4; ++i) s += wsum[i];
        block_sums[blockIdx.x] = s;
    }
}

__global__ __launch_bounds__(256) void cbow_finish(
    const float* __restrict__ block_sums, float* __restrict__ out)
{
    __shared__ double sh[256];
    double s = 0.0;
    for (int i = threadIdx.x; i < NBLOCKS; i += 256) s += (double)block_sums[i];
    sh[threadIdx.x] = s;
    __syncthreads();
    #pragma unroll
    for (int stride = 128; stride >= 1; stride >>= 1) {
        if (threadIdx.x < stride) sh[threadIdx.x] += sh[threadIdx.x + stride];
        __syncthreads();
    }
    if (threadIdx.x == 0) {
        out[0] = (float)(-sh[0] / (double)CBOW_B);
    }
}

extern "C" void kernel_launch(void* const* d_in, const int* in_sizes, int n_in,
                              void* d_out, int out_size, void* d_ws, size_t ws_size,
                              hipStream_t stream) {
    const int*   context = (const int*)d_in[0];   // [B, W]
    const int*   target  = (const int*)d_in[1];   // [B]
    const int*   noise   = (const int*)d_in[2];   // [B, K]
    const float* emb_w   = (const float*)d_in[3]; // [V, D]
    const float* ctx_w   = (const float*)d_in[4]; // [V, D]
    float*       out     = (float*)d_out;
    float*       block_sums = (float*)d_ws;       // NBLOCKS floats = 4 KiB

    cbow_main<<<NBLOCKS, 256, 0, stream>>>(context, target, noise, emb_w, ctx_w,
                                           block_sums);
    cbow_finish<<<1, 256, 0, stream>>>(block_sums, out);
}